// Round 6
// baseline (489.654 us; speedup 1.0000x reference)
//
#include <hip/hip_runtime.h>
#include <math.h>

#define NN 50000
#define NE 500000
#define NREL 4
#define D 128
#define RSZ 512                 // dst-range size (one bin)
#define NRANGE 98               // ceil(NN/512)
#define NBK (NREL * NRANGE)     // 392 sort blocks
#define BCAP 6144               // per-(range,rel) csr capacity (mean 5120, +14 sigma)
#define NCH 128                 // edge chunks per relation
#define CH 3907                 // edges per chunk (128*3907 >= 500000)
#define FCAP 96                 // frag capacity per (chunk,bin): mean 40, +9 sigma
#define CAST_BLKS 6250          // NN*D/4/256
static constexpr float BN_EPS = 1e-5f;

typedef __attribute__((ext_vector_type(8))) _Float16 half8;
typedef __attribute__((ext_vector_type(4))) float f32x4;

__device__ __forceinline__ unsigned short f2h_bits(float f) {
    _Float16 h = (_Float16)f;  // v_cvt_f16_f32 (RTNE)
    return __builtin_bit_cast(unsigned short, h);
}
__device__ __forceinline__ float hi2f(unsigned p) {  // f16 in high 16 bits -> f32
    return (float)__builtin_bit_cast(_Float16, (unsigned short)(p >> 16));
}

// ---------------- fused prologue: cast x->f16, weight transpose+cast, bias sums, bnsum zero ----
__global__ __launch_bounds__(256) void k_pre(const float* __restrict__ x,
                                             const float* __restrict__ W1, const float* __restrict__ W2,
                                             const float* __restrict__ l1W, const float* __restrict__ b1,
                                             const float* __restrict__ b2,
                                             unsigned short* __restrict__ xb,
                                             unsigned short* __restrict__ Wt1,
                                             unsigned short* __restrict__ Wt2,
                                             unsigned short* __restrict__ Wt3,
                                             float* __restrict__ bs1, float* __restrict__ bs2,
                                             float* __restrict__ bnsum) {
    int blk = blockIdx.x, tid = threadIdx.x;
    if (blk < CAST_BLKS) {
        int i = blk * 256 + tid;
        float4 v = *(const float4*)(x + (size_t)i * 4);
        unsigned short u[4] = {f2h_bits(v.x), f2h_bits(v.y), f2h_bits(v.z), f2h_bits(v.w)};
        *(ushort4*)(xb + (size_t)i * 4) = *(ushort4*)u;
    } else if (blk < CAST_BLKS + 256) {
        int i = (blk - CAST_BLKS) * 256 + tid;  // [0, 65536)
        int kk = i & 511, n = i >> 9;           // coalesced stores along kk
        Wt1[n * 512 + kk] = f2h_bits(W1[kk * 128 + n]);
        Wt2[n * 512 + kk] = f2h_bits(W2[kk * 128 + n]);
    } else if (blk < CAST_BLKS + 320) {
        int i = (blk - CAST_BLKS - 256) * 256 + tid;  // [0, 16384)
        int kk = i & 127, n = i >> 7;
        Wt3[n * 128 + kk] = f2h_bits(l1W[kk * 128 + n]);
    } else {
        if (tid < 128) {
            bs1[tid] = b1[tid] + b1[128 + tid] + b1[256 + tid] + b1[384 + tid];
            bs2[tid] = b2[tid] + b2[128 + tid] + b2[256 + tid] + b2[384 + tid];
        }
        bnsum[tid] = 0.f;  // 256 floats
    }
}

// ---------------- pass A: bin edges into (chunk, range) fragment windows ----------------
// packed = src | dstlocal<<16 (src<50000 fits 16 bits, dstlocal 9 bits)
__global__ __launch_bounds__(256) void k_bin(const int* __restrict__ ei,
                                             int* __restrict__ frag,
                                             int* __restrict__ cntg) {
    int c = blockIdx.x, r = blockIdx.y;
    const int* srcp = ei + r * 2 * NE;
    const int* dstp = srcp + NE;
    __shared__ int bins[NRANGE * FCAP];  // 37.6 KB
    __shared__ int cnt[NRANGE];
    int tid = threadIdx.x;
    for (int i = tid; i < NRANGE; i += 256) cnt[i] = 0;
    __syncthreads();
    int e0 = c * CH, e1 = min(e0 + CH, NE);
    for (int e = e0 + tid; e < e1; e += 256) {
        int d = dstp[e];
        int s = srcp[e];
        int q = d >> 9;
        int pos = atomicAdd(&cnt[q], 1);
        if (pos < FCAP) bins[q * FCAP + pos] = s | ((d & 511) << 16);
    }
    __syncthreads();
    int w = tid >> 6, lane = tid & 63;
    for (int q = w; q < NRANGE; q += 4) {
        int k = min(cnt[q], FCAP);
        int gbase = ((r * NRANGE + q) * NCH + c) * FCAP;
        for (int i = lane; i < k; i += 64) frag[gbase + i] = bins[q * FCAP + i];
    }
    for (int q = tid; q < NRANGE; q += 256) cntg[(r * NRANGE + q) * NCH + c] = min(cnt[q], FCAP);
}

// ---------------- pass B: per (range, rel) counting-sort into CSR ----------------
__global__ __launch_bounds__(512) void k_sortb(const int* __restrict__ frag,
                                               const int* __restrict__ cntg,
                                               unsigned short* __restrict__ csr,
                                               int* __restrict__ rstart,
                                               int* __restrict__ rend,
                                               float* __restrict__ dinv) {
    int q = blockIdx.x, r = blockIdx.y;
    int blk = r * NRANGE + q;
    int n0 = q * RSZ;
    int nrows = min(RSZ, NN - n0);
    __shared__ int cnts[NCH], cbase[NCH];
    __shared__ int stage[BCAP];          // 24 KB
    __shared__ unsigned short csr_s[BCAP];
    __shared__ int hist[RSZ], off[RSZ], cnt2[RSZ];
    int tid = threadIdx.x;
    hist[tid] = 0;
    cnt2[tid] = 0;
    if (tid < NCH) cnts[tid] = cntg[blk * NCH + tid];
    __syncthreads();
    // exclusive scan of 128 chunk counts
    if (tid < NCH) cbase[tid] = cnts[tid];
    __syncthreads();
    for (int d = 1; d < NCH; d <<= 1) {
        int t = 0;
        if (tid < NCH && tid >= d) t = cbase[tid - d];
        __syncthreads();
        if (tid < NCH) cbase[tid] += t;
        __syncthreads();
    }
    if (tid < NCH) cbase[tid] -= cnts[tid];
    __syncthreads();
    int tot = cbase[NCH - 1] + cnts[NCH - 1];
    // parallel gather of all 128 fragment windows (4 threads per chunk)
    {
        int g = tid >> 2, l = tid & 3;
        int k = cnts[g], cb = cbase[g];
        int gbase = (blk * NCH + g) * FCAP;
        for (int i = l; i < k; i += 4)
            if (cb + i < BCAP) stage[cb + i] = frag[gbase + i];
    }
    __syncthreads();
    if (tot > BCAP) tot = BCAP;
    // histogram over dst-local
    for (int i = tid; i < tot; i += 512) atomicAdd(&hist[(stage[i] >> 16) & 511], 1);
    __syncthreads();
    int h = hist[tid];
    if (tid < nrows) dinv[r * NN + n0 + tid] = rsqrtf((float)(h + 1));  // +1 self loop
    // inclusive scan -> exclusive offsets
    off[tid] = h;
    __syncthreads();
    for (int d = 1; d < RSZ; d <<= 1) {
        int t = (tid >= d) ? off[tid - d] : 0;
        __syncthreads();
        off[tid] += t;
        __syncthreads();
    }
    int excl = off[tid] - h;
    __syncthreads();
    off[tid] = excl;
    int base = blk * BCAP;
    if (tid < nrows) {
        rstart[r * NN + n0 + tid] = base + excl;
        rend[r * NN + n0 + tid] = base + excl + h;
    }
    __syncthreads();
    // counting-sort into LDS
    for (int i = tid; i < tot; i += 512) {
        int v = stage[i];
        int dl = (v >> 16) & 511;
        int p = atomicAdd(&cnt2[dl], 1);
        csr_s[off[dl] + p] = (unsigned short)(v & 0xFFFF);
    }
    __syncthreads();
    // coalesced block-private write-out
    for (int i = tid; i < tot; i += 512) csr[base + i] = csr_s[i];
}

// ---------------- fill packed per-edge words: wpack[i] = src | f16(dinv[r][src])<<16 ----------
__global__ __launch_bounds__(256) void k_wei(const unsigned short* __restrict__ csr,
                                             const float* __restrict__ dinv,
                                             unsigned* __restrict__ wpack) {
    int gi = blockIdx.x * 256 + threadIdx.x;
    int r = gi / (NRANGE * BCAP);
    int s = csr[gi];                       // garbage in gaps is harmless (masked in k_agg)
    float w = dinv[r * NN + min(s, NN - 1)];
    wpack[gi] = (unsigned)s | ((unsigned)f2h_bits(w) << 16);
}

// ---------------- aggregation: wave = node, quarter = relation (R3 structure, 67us) ----------
// 50K waves, each with 4 independent gather chains (one per relation) in one instruction
// stream -> 8 row-misses in flight per batch. Quarter q (16 lanes, t=lane&15) owns relation
// q's full 128 cols (8 per lane): no cross-lane reduce, dense 1KB/wave coalesced store.
// Self-loop folded into acc init. One packed 4B word per edge, distributed by shuffles.
__global__ __launch_bounds__(256) void k_agg(const unsigned short* __restrict__ in,  // f16 [NN][128]
                                             const unsigned* __restrict__ wpack,
                                             const int* __restrict__ rstart,
                                             const int* __restrict__ rend,
                                             const float* __restrict__ dinv,         // [NREL][NN]
                                             unsigned short* __restrict__ Acat) {    // f16 [NN][512]
    int wave = threadIdx.x >> 6, lane = threadIdx.x & 63;
    int n = blockIdx.x * 4 + wave;
    if (n >= NN) return;
    int t = lane & 15;
    int base = lane & 48;  // q<<4
    int nb = (base >> 4) * NN + n;  // q*NN + n
    const half8* in8 = (const half8*)in;
    float wn = dinv[nb];
    int start = rstart[nb];
    int deg = rend[nb] - start;
    // wave-uniform max degree over the 4 quarters -> branchless uniform trip
    int dm = deg;
    dm = max(dm, __shfl_xor(dm, 16));
    dm = max(dm, __shfl_xor(dm, 32));
    // acc init = self-loop contribution (wn * x_n); final scale by wn at the end
    half8 us = in8[(size_t)n * 16 + t];
    float a[8];
#pragma unroll
    for (int j = 0; j < 8; j++) a[j] = wn * (float)us[j];

    for (int w0 = 0; w0 < dm; w0 += 16) {
        // cooperative window: lane holds edge (w0 + t) of ITS quarter's list
        int li = w0 + t;
        int gi = min(start + li, NBK * BCAP - 1);
        unsigned pv = wpack[gi];
        if (li >= deg) pv = 0u;  // src=0, w=+0.0 (row 0 load, L1-hot, adds zero)
        // batch A: edges 0..7 of this window
        unsigned p0 = __shfl(pv, base + 0), p1 = __shfl(pv, base + 1);
        unsigned p2 = __shfl(pv, base + 2), p3 = __shfl(pv, base + 3);
        unsigned p4 = __shfl(pv, base + 4), p5 = __shfl(pv, base + 5);
        unsigned p6 = __shfl(pv, base + 6), p7 = __shfl(pv, base + 7);
        {
            half8 r0 = in8[(p0 & 0xFFFFu) * 16 + t];
            half8 r1 = in8[(p1 & 0xFFFFu) * 16 + t];
            half8 r2 = in8[(p2 & 0xFFFFu) * 16 + t];
            half8 r3 = in8[(p3 & 0xFFFFu) * 16 + t];
            half8 r4 = in8[(p4 & 0xFFFFu) * 16 + t];
            half8 r5 = in8[(p5 & 0xFFFFu) * 16 + t];
            half8 r6 = in8[(p6 & 0xFFFFu) * 16 + t];
            half8 r7 = in8[(p7 & 0xFFFFu) * 16 + t];
            float w0f = hi2f(p0), w1f = hi2f(p1), w2f = hi2f(p2), w3f = hi2f(p3);
            float w4f = hi2f(p4), w5f = hi2f(p5), w6f = hi2f(p6), w7f = hi2f(p7);
#pragma unroll
            for (int j = 0; j < 8; j++) a[j] = fmaf((float)r0[j], w0f, a[j]);
#pragma unroll
            for (int j = 0; j < 8; j++) a[j] = fmaf((float)r1[j], w1f, a[j]);
#pragma unroll
            for (int j = 0; j < 8; j++) a[j] = fmaf((float)r2[j], w2f, a[j]);
#pragma unroll
            for (int j = 0; j < 8; j++) a[j] = fmaf((float)r3[j], w3f, a[j]);
#pragma unroll
            for (int j = 0; j < 8; j++) a[j] = fmaf((float)r4[j], w4f, a[j]);
#pragma unroll
            for (int j = 0; j < 8; j++) a[j] = fmaf((float)r5[j], w5f, a[j]);
#pragma unroll
            for (int j = 0; j < 8; j++) a[j] = fmaf((float)r6[j], w6f, a[j]);
#pragma unroll
            for (int j = 0; j < 8; j++) a[j] = fmaf((float)r7[j], w7f, a[j]);
        }
        if (w0 + 8 >= dm) continue;  // uniform branch: skip batch B if window <= 8 edges
        // batch B: edges 8..15
        p0 = __shfl(pv, base + 8);  p1 = __shfl(pv, base + 9);
        p2 = __shfl(pv, base + 10); p3 = __shfl(pv, base + 11);
        p4 = __shfl(pv, base + 12); p5 = __shfl(pv, base + 13);
        p6 = __shfl(pv, base + 14); p7 = __shfl(pv, base + 15);
        {
            half8 r0 = in8[(p0 & 0xFFFFu) * 16 + t];
            half8 r1 = in8[(p1 & 0xFFFFu) * 16 + t];
            half8 r2 = in8[(p2 & 0xFFFFu) * 16 + t];
            half8 r3 = in8[(p3 & 0xFFFFu) * 16 + t];
            half8 r4 = in8[(p4 & 0xFFFFu) * 16 + t];
            half8 r5 = in8[(p5 & 0xFFFFu) * 16 + t];
            half8 r6 = in8[(p6 & 0xFFFFu) * 16 + t];
            half8 r7 = in8[(p7 & 0xFFFFu) * 16 + t];
            float w0f = hi2f(p0), w1f = hi2f(p1), w2f = hi2f(p2), w3f = hi2f(p3);
            float w4f = hi2f(p4), w5f = hi2f(p5), w6f = hi2f(p6), w7f = hi2f(p7);
#pragma unroll
            for (int j = 0; j < 8; j++) a[j] = fmaf((float)r0[j], w0f, a[j]);
#pragma unroll
            for (int j = 0; j < 8; j++) a[j] = fmaf((float)r1[j], w1f, a[j]);
#pragma unroll
            for (int j = 0; j < 8; j++) a[j] = fmaf((float)r2[j], w2f, a[j]);
#pragma unroll
            for (int j = 0; j < 8; j++) a[j] = fmaf((float)r3[j], w3f, a[j]);
#pragma unroll
            for (int j = 0; j < 8; j++) a[j] = fmaf((float)r4[j], w4f, a[j]);
#pragma unroll
            for (int j = 0; j < 8; j++) a[j] = fmaf((float)r5[j], w5f, a[j]);
#pragma unroll
            for (int j = 0; j < 8; j++) a[j] = fmaf((float)r6[j], w6f, a[j]);
#pragma unroll
            for (int j = 0; j < 8; j++) a[j] = fmaf((float)r7[j], w7f, a[j]);
        }
    }
    // final dst scale + write: 64 lanes x 16B = 1KB contiguous per node
    _Float16 ob[8];
#pragma unroll
    for (int j = 0; j < 8; j++) ob[j] = (_Float16)(wn * a[j]);
    *(half8*)(Acat + (size_t)n * 512 + (base << 3) + t * 8) = *(half8*)ob;
}

// ---------------- MFMA GEMM: C[NN][128] = relu(A[NN][K] @ W[K][128] + bias) (f16 in/out) ----
// RE-GRIDDED: 1 wave = 16 rows x 128 cols (mf dim removed), block = 64 rows, grid = 782
// blocks (~3/CU). Old 196-block version left 3/4 of CUs idle -> ~50us; this streams A at
// full memory rate.
template <int K, bool STATS>
__global__ __launch_bounds__(256) void k_mm(const unsigned short* __restrict__ A,
                                            const unsigned short* __restrict__ Bt,
                                            const float* __restrict__ bias,
                                            unsigned short* __restrict__ C,
                                            float* __restrict__ bnsum) {
    int tid = threadIdx.x;
    int w = tid >> 6, lane = tid & 63;
    int ln = lane & 15, quad = lane >> 4;
    int m0 = blockIdx.x * 64 + w * 16;  // 16 rows per wave

    f32x4 acc[8];
#pragma unroll
    for (int b = 0; b < 8; b++) acc[b] = (f32x4){0.f, 0.f, 0.f, 0.f};

    size_t arow = (size_t)min(m0 + ln, NN - 1) * K;  // clamp; garbage rows guarded at store
    size_t brow[8];
#pragma unroll
    for (int nf = 0; nf < 8; nf++) brow[nf] = (size_t)(nf * 16 + ln) * K;

    for (int k0 = 0; k0 < K; k0 += 32) {
        int kof = k0 + quad * 8;
        half8 af = *(const half8*)(A + arow + kof);
#pragma unroll
        for (int nf = 0; nf < 8; nf++) {
            half8 bf = *(const half8*)(Bt + brow[nf] + kof);
            acc[nf] = __builtin_amdgcn_mfma_f32_16x16x32_f16(af, bf, acc[nf], 0, 0, 0);
        }
    }

    float bs[8];
#pragma unroll
    for (int nf = 0; nf < 8; nf++) bs[nf] = bias[nf * 16 + ln];
    float sn[8], qn[8];
#pragma unroll
    for (int nf = 0; nf < 8; nf++) { sn[nf] = 0.f; qn[nf] = 0.f; }

#pragma unroll
    for (int nf = 0; nf < 8; nf++)
#pragma unroll
        for (int rg = 0; rg < 4; rg++) {
            int m = m0 + quad * 4 + rg;
            if (m < NN) {
                float v = fmaxf(acc[nf][rg] + bs[nf], 0.f);
                if (STATS) { sn[nf] += v; qn[nf] += v * v; }
                C[(size_t)m * 128 + nf * 16 + ln] = f2h_bits(v);
            }
        }

    if (STATS) {
#pragma unroll
        for (int nf = 0; nf < 8; nf++) {
            float s = sn[nf], q = qn[nf];
            s += __shfl_xor(s, 16); s += __shfl_xor(s, 32);
            q += __shfl_xor(q, 16); q += __shfl_xor(q, 32);
            if (quad == 0) {
                unsafeAtomicAdd(&bnsum[nf * 16 + ln], s);
                unsafeAtomicAdd(&bnsum[128 + nf * 16 + ln], q);
            }
        }
    }
}

// ---------------- final: BN affine from bnsum + relu(BN(R2)@l1W+l1b)@l2W+l2b ----------------
// Same re-grid: 1 wave = 16 rows, grid = 782 blocks.
__global__ __launch_bounds__(256) void k_final(const unsigned short* __restrict__ R2,
                                               const float* __restrict__ bnsum,
                                               const float* __restrict__ gamma,
                                               const float* __restrict__ beta,
                                               const unsigned short* __restrict__ Wt3,
                                               const float* __restrict__ l1b,
                                               const float* __restrict__ l2W,
                                               const float* __restrict__ l2b,
                                               float* __restrict__ out) {
    __shared__ float bnp_s[256];
    int tid = threadIdx.x;
    if (tid < 128) {
        float mean = bnsum[tid] / (float)NN;
        float var = bnsum[128 + tid] / (float)NN - mean * mean;
        float sc = gamma[tid] * rsqrtf(var + BN_EPS);
        bnp_s[tid] = sc;
        bnp_s[128 + tid] = beta[tid] - mean * sc;
    }
    __syncthreads();
    int w = tid >> 6, lane = tid & 63;
    int ln = lane & 15, quad = lane >> 4;
    int m0 = blockIdx.x * 64 + w * 16;

    f32x4 acc[8];
#pragma unroll
    for (int b = 0; b < 8; b++) acc[b] = (f32x4){0.f, 0.f, 0.f, 0.f};

    size_t arow = (size_t)min(m0 + ln, NN - 1) * 128;
    size_t brow[8];
#pragma unroll
    for (int nf = 0; nf < 8; nf++) brow[nf] = (size_t)(nf * 16 + ln) * 128;

    for (int k0 = 0; k0 < 128; k0 += 32) {
        int kof = k0 + quad * 8;
        float scv[8], shv[8];
#pragma unroll
        for (int j = 0; j < 8; j++) {
            scv[j] = bnp_s[kof + j];
            shv[j] = bnp_s[128 + kof + j];
        }
        half8 rv = *(const half8*)(R2 + arow + kof);
        _Float16 ab[8];
#pragma unroll
        for (int j = 0; j < 8; j++)
            ab[j] = (_Float16)(fmaf((float)rv[j], scv[j], shv[j]));
        half8 af = *(half8*)ab;
#pragma unroll
        for (int nf = 0; nf < 8; nf++) {
            half8 bf = *(const half8*)(Wt3 + brow[nf] + kof);
            acc[nf] = __builtin_amdgcn_mfma_f32_16x16x32_f16(af, bf, acc[nf], 0, 0, 0);
        }
    }

    float b1v[8], w0[8], w1[8];
#pragma unroll
    for (int nf = 0; nf < 8; nf++) {
        int n = nf * 16 + ln;
        b1v[nf] = l1b[n];
        w0[nf] = l2W[n * 2];
        w1[nf] = l2W[n * 2 + 1];
    }
    float ob0 = l2b[0], ob1 = l2b[1];
#pragma unroll
    for (int rg = 0; rg < 4; rg++) {
        float p0 = 0.f, p1 = 0.f;
#pragma unroll
        for (int nf = 0; nf < 8; nf++) {
            float y = fmaxf(acc[nf][rg] + b1v[nf], 0.f);
            p0 += y * w0[nf];
            p1 += y * w1[nf];
        }
        p0 += __shfl_xor(p0, 1); p0 += __shfl_xor(p0, 2);
        p0 += __shfl_xor(p0, 4); p0 += __shfl_xor(p0, 8);
        p1 += __shfl_xor(p1, 1); p1 += __shfl_xor(p1, 2);
        p1 += __shfl_xor(p1, 4); p1 += __shfl_xor(p1, 8);
        int m = m0 + quad * 4 + rg;
        if (ln == 0 && m < NN) {
            out[(size_t)m * 2 + 0] = p0 + ob0;
            out[(size_t)m * 2 + 1] = p1 + ob1;
        }
    }
}

extern "C" void kernel_launch(void* const* d_in, const int* in_sizes, int n_in,
                              void* d_out, int out_size, void* d_ws, size_t ws_size,
                              hipStream_t stream) {
    const float* x = (const float*)d_in[0];
    const int* ei = (const int*)d_in[1];
    const float* W1 = (const float*)d_in[2];
    const float* b1 = (const float*)d_in[3];
    const float* W2 = (const float*)d_in[4];
    const float* b2 = (const float*)d_in[5];
    const float* gamma = (const float*)d_in[6];
    const float* beta = (const float*)d_in[7];
    const float* l1W = (const float*)d_in[8];
    const float* l1b = (const float*)d_in[9];
    const float* l2W = (const float*)d_in[10];
    const float* l2b = (const float*)d_in[11];
    float* out = (float*)d_out;

    char* ws = (char*)d_ws;
    size_t off = 0;
    auto alloc = [&](size_t bytes) {
        void* p = ws + off;
        off += (bytes + 255) & ~(size_t)255;
        return p;
    };
    float* dinv = (float*)alloc((size_t)NREL * NN * sizeof(float));
    int* rstart = (int*)alloc((size_t)NREL * NN * sizeof(int));
    int* rend = (int*)alloc((size_t)NREL * NN * sizeof(int));
    unsigned short* csr = (unsigned short*)alloc((size_t)NBK * BCAP * 2);            // 4.8 MB
    unsigned* wpack = (unsigned*)alloc((size_t)NBK * BCAP * 4);                      // 9.6 MB
    unsigned short* xb = (unsigned short*)alloc((size_t)NN * D * 2);                 // 12.8 MB
    unsigned short* Acat = (unsigned short*)alloc((size_t)NN * 512 * 2);             // 51.2 MB
    unsigned short* h1b = (unsigned short*)alloc((size_t)NN * D * 2);                // 12.8 MB
    unsigned short* R2b = (unsigned short*)alloc((size_t)NN * D * 2);                // 12.8 MB
    unsigned short* Wt1 = (unsigned short*)alloc(128 * 512 * 2);
    unsigned short* Wt2 = (unsigned short*)alloc(128 * 512 * 2);
    unsigned short* Wt3 = (unsigned short*)alloc(128 * 128 * 2);
    float* bs1 = (float*)alloc(128 * sizeof(float));
    float* bs2 = (float*)alloc(128 * sizeof(float));
    float* bnsum = (float*)alloc(256 * sizeof(float));

    // frag/cntg alias Acat's storage (dead once k_sortb completes; Acat first written by k_agg)
    int* frag = (int*)Acat;                                       // 19.3 MB
    int* cntg = frag + (size_t)NREL * NRANGE * NCH * FCAP;        // 0.2 MB

    k_pre<<<CAST_BLKS + 321, 256, 0, stream>>>(x, W1, W2, l1W, b1, b2, xb, Wt1, Wt2, Wt3,
                                               bs1, bs2, bnsum);
    dim3 bgrid(NCH, NREL);
    k_bin<<<bgrid, 256, 0, stream>>>(ei, frag, cntg);
    dim3 sgrid(NRANGE, NREL);
    k_sortb<<<sgrid, 512, 0, stream>>>(frag, cntg, csr, rstart, rend, dinv);
    k_wei<<<(NBK * BCAP) / 256, 256, 0, stream>>>(csr, dinv, wpack);

    int agrid = (NN + 3) / 4;     // wave = node (all 4 relations)
    int mgrid = (NN + 63) / 64;   // wave = 16 rows
    // layer 1: aggregate x per relation -> Acat (concat), then one K=512 GEMM
    k_agg<<<agrid, 256, 0, stream>>>(xb, wpack, rstart, rend, dinv, Acat);
    k_mm<512, false><<<mgrid, 256, 0, stream>>>(Acat, Wt1, bs1, h1b, nullptr);
    // layer 2
    k_agg<<<agrid, 256, 0, stream>>>(h1b, wpack, rstart, rend, dinv, Acat);
    k_mm<512, true><<<mgrid, 256, 0, stream>>>(Acat, Wt2, bs2, R2b, bnsum);
    // fused BN + MLP head
    k_final<<<mgrid, 256, 0, stream>>>(R2b, bnsum, gamma, beta, Wt3, l1b, l2W, l2b, out);
}

// Round 7
// 395.080 us; speedup vs baseline: 1.2394x; 1.2394x over previous
//
#include <hip/hip_runtime.h>
#include <math.h>

#define NN 50000
#define NE 500000
#define NREL 4
#define D 128
#define RSZ 512                 // dst-range size (one bin)
#define NRANGE 98               // ceil(NN/512)
#define NBK (NREL * NRANGE)     // 392 sort blocks
#define BCAP 6144               // per-(range,rel) csr capacity (mean 5120, +14 sigma)
#define NCH 128                 // edge chunks per relation
#define CH 3907                 // edges per chunk (128*3907 >= 500000)
#define FCAP 96                 // frag capacity per (chunk,bin): mean 40, +9 sigma
#define CAST_BLKS 6250          // NN*D/4/256
static constexpr float BN_EPS = 1e-5f;

typedef __attribute__((ext_vector_type(8))) _Float16 half8;
typedef __attribute__((ext_vector_type(4))) float f32x4;

__device__ __forceinline__ unsigned short f2h_bits(float f) {
    _Float16 h = (_Float16)f;  // v_cvt_f16_f32 (RTNE)
    return __builtin_bit_cast(unsigned short, h);
}
__device__ __forceinline__ float hi2f(unsigned p) {  // f16 in high 16 bits -> f32
    return (float)__builtin_bit_cast(_Float16, (unsigned short)(p >> 16));
}

// ---------------- fused prologue: cast x->f16, weight transpose+cast, bias sums, bnsum zero ----
__global__ __launch_bounds__(256) void k_pre(const float* __restrict__ x,
                                             const float* __restrict__ W1, const float* __restrict__ W2,
                                             const float* __restrict__ l1W, const float* __restrict__ b1,
                                             const float* __restrict__ b2,
                                             unsigned short* __restrict__ xb,
                                             unsigned short* __restrict__ Wt1,
                                             unsigned short* __restrict__ Wt2,
                                             unsigned short* __restrict__ Wt3,
                                             float* __restrict__ bs1, float* __restrict__ bs2,
                                             float* __restrict__ bnsum) {
    int blk = blockIdx.x, tid = threadIdx.x;
    if (blk < CAST_BLKS) {
        int i = blk * 256 + tid;
        float4 v = *(const float4*)(x + (size_t)i * 4);
        unsigned short u[4] = {f2h_bits(v.x), f2h_bits(v.y), f2h_bits(v.z), f2h_bits(v.w)};
        *(ushort4*)(xb + (size_t)i * 4) = *(ushort4*)u;
    } else if (blk < CAST_BLKS + 256) {
        int i = (blk - CAST_BLKS) * 256 + tid;  // [0, 65536)
        int kk = i & 511, n = i >> 9;           // coalesced stores along kk
        Wt1[n * 512 + kk] = f2h_bits(W1[kk * 128 + n]);
        Wt2[n * 512 + kk] = f2h_bits(W2[kk * 128 + n]);
    } else if (blk < CAST_BLKS + 320) {
        int i = (blk - CAST_BLKS - 256) * 256 + tid;  // [0, 16384)
        int kk = i & 127, n = i >> 7;
        Wt3[n * 128 + kk] = f2h_bits(l1W[kk * 128 + n]);
    } else {
        if (tid < 128) {
            bs1[tid] = b1[tid] + b1[128 + tid] + b1[256 + tid] + b1[384 + tid];
            bs2[tid] = b2[tid] + b2[128 + tid] + b2[256 + tid] + b2[384 + tid];
        }
        bnsum[tid] = 0.f;  // 256 floats
    }
}

// ---------------- pass A: bin edges into (chunk, range) fragment windows ----------------
// packed = src | dstlocal<<16 (src<50000 fits 16 bits, dstlocal 9 bits)
__global__ __launch_bounds__(256) void k_bin(const int* __restrict__ ei,
                                             int* __restrict__ frag,
                                             int* __restrict__ cntg) {
    int c = blockIdx.x, r = blockIdx.y;
    const int* srcp = ei + r * 2 * NE;
    const int* dstp = srcp + NE;
    __shared__ int bins[NRANGE * FCAP];  // 37.6 KB
    __shared__ int cnt[NRANGE];
    int tid = threadIdx.x;
    for (int i = tid; i < NRANGE; i += 256) cnt[i] = 0;
    __syncthreads();
    int e0 = c * CH, e1 = min(e0 + CH, NE);
    for (int e = e0 + tid; e < e1; e += 256) {
        int d = dstp[e];
        int s = srcp[e];
        int q = d >> 9;
        int pos = atomicAdd(&cnt[q], 1);
        if (pos < FCAP) bins[q * FCAP + pos] = s | ((d & 511) << 16);
    }
    __syncthreads();
    int w = tid >> 6, lane = tid & 63;
    for (int q = w; q < NRANGE; q += 4) {
        int k = min(cnt[q], FCAP);
        int gbase = ((r * NRANGE + q) * NCH + c) * FCAP;
        for (int i = lane; i < k; i += 64) frag[gbase + i] = bins[q * FCAP + i];
    }
    for (int q = tid; q < NRANGE; q += 256) cntg[(r * NRANGE + q) * NCH + c] = min(cnt[q], FCAP);
}

// ---------------- pass B: per (range, rel) counting-sort into CSR ----------------
__global__ __launch_bounds__(512) void k_sortb(const int* __restrict__ frag,
                                               const int* __restrict__ cntg,
                                               unsigned short* __restrict__ csr,
                                               int* __restrict__ rstart,
                                               int* __restrict__ rend,
                                               float* __restrict__ dinv) {
    int q = blockIdx.x, r = blockIdx.y;
    int blk = r * NRANGE + q;
    int n0 = q * RSZ;
    int nrows = min(RSZ, NN - n0);
    __shared__ int cnts[NCH], cbase[NCH];
    __shared__ int stage[BCAP];          // 24 KB
    __shared__ unsigned short csr_s[BCAP];
    __shared__ int hist[RSZ], off[RSZ], cnt2[RSZ];
    int tid = threadIdx.x;
    hist[tid] = 0;
    cnt2[tid] = 0;
    if (tid < NCH) cnts[tid] = cntg[blk * NCH + tid];
    __syncthreads();
    // exclusive scan of 128 chunk counts
    if (tid < NCH) cbase[tid] = cnts[tid];
    __syncthreads();
    for (int d = 1; d < NCH; d <<= 1) {
        int t = 0;
        if (tid < NCH && tid >= d) t = cbase[tid - d];
        __syncthreads();
        if (tid < NCH) cbase[tid] += t;
        __syncthreads();
    }
    if (tid < NCH) cbase[tid] -= cnts[tid];
    __syncthreads();
    int tot = cbase[NCH - 1] + cnts[NCH - 1];
    // parallel gather of all 128 fragment windows (4 threads per chunk)
    {
        int g = tid >> 2, l = tid & 3;
        int k = cnts[g], cb = cbase[g];
        int gbase = (blk * NCH + g) * FCAP;
        for (int i = l; i < k; i += 4)
            if (cb + i < BCAP) stage[cb + i] = frag[gbase + i];
    }
    __syncthreads();
    if (tot > BCAP) tot = BCAP;
    // histogram over dst-local
    for (int i = tid; i < tot; i += 512) atomicAdd(&hist[(stage[i] >> 16) & 511], 1);
    __syncthreads();
    int h = hist[tid];
    if (tid < nrows) dinv[r * NN + n0 + tid] = rsqrtf((float)(h + 1));  // +1 self loop
    // inclusive scan -> exclusive offsets
    off[tid] = h;
    __syncthreads();
    for (int d = 1; d < RSZ; d <<= 1) {
        int t = (tid >= d) ? off[tid - d] : 0;
        __syncthreads();
        off[tid] += t;
        __syncthreads();
    }
    int excl = off[tid] - h;
    __syncthreads();
    off[tid] = excl;
    int base = blk * BCAP;
    if (tid < nrows) {
        rstart[r * NN + n0 + tid] = base + excl;
        rend[r * NN + n0 + tid] = base + excl + h;
    }
    __syncthreads();
    // counting-sort into LDS
    for (int i = tid; i < tot; i += 512) {
        int v = stage[i];
        int dl = (v >> 16) & 511;
        int p = atomicAdd(&cnt2[dl], 1);
        csr_s[off[dl] + p] = (unsigned short)(v & 0xFFFF);
    }
    __syncthreads();
    // coalesced block-private write-out
    for (int i = tid; i < tot; i += 512) csr[base + i] = csr_s[i];
}

// ---------------- fill packed per-edge words: wpack[i] = src | f16(dinv[r][src])<<16 ----------
__global__ __launch_bounds__(256) void k_wei(const unsigned short* __restrict__ csr,
                                             const float* __restrict__ dinv,
                                             unsigned* __restrict__ wpack) {
    int gi = blockIdx.x * 256 + threadIdx.x;
    int r = gi / (NRANGE * BCAP);
    int s = csr[gi];                       // garbage in gaps is harmless (masked in k_agg)
    float w = dinv[r * NN + min(s, NN - 1)];
    wpack[gi] = (unsigned)s | ((unsigned)f2h_bits(w) << 16);
}

// ---------------- aggregation: wave = node, quarter = relation (R3 structure, 67us) ----------
__global__ __launch_bounds__(256) void k_agg(const unsigned short* __restrict__ in,  // f16 [NN][128]
                                             const unsigned* __restrict__ wpack,
                                             const int* __restrict__ rstart,
                                             const int* __restrict__ rend,
                                             const float* __restrict__ dinv,         // [NREL][NN]
                                             unsigned short* __restrict__ Acat) {    // f16 [NN][512]
    int wave = threadIdx.x >> 6, lane = threadIdx.x & 63;
    int n = blockIdx.x * 4 + wave;
    if (n >= NN) return;
    int t = lane & 15;
    int base = lane & 48;  // q<<4
    int nb = (base >> 4) * NN + n;  // q*NN + n
    const half8* in8 = (const half8*)in;
    float wn = dinv[nb];
    int start = rstart[nb];
    int deg = rend[nb] - start;
    // wave-uniform max degree over the 4 quarters -> branchless uniform trip
    int dm = deg;
    dm = max(dm, __shfl_xor(dm, 16));
    dm = max(dm, __shfl_xor(dm, 32));
    // acc init = self-loop contribution (wn * x_n); final scale by wn at the end
    half8 us = in8[(size_t)n * 16 + t];
    float a[8];
#pragma unroll
    for (int j = 0; j < 8; j++) a[j] = wn * (float)us[j];

    for (int w0 = 0; w0 < dm; w0 += 16) {
        // cooperative window: lane holds edge (w0 + t) of ITS quarter's list
        int li = w0 + t;
        int gi = min(start + li, NBK * BCAP - 1);
        unsigned pv = wpack[gi];
        if (li >= deg) pv = 0u;  // src=0, w=+0.0 (row 0 load, L1-hot, adds zero)
        // batch A: edges 0..7 of this window
        unsigned p0 = __shfl(pv, base + 0), p1 = __shfl(pv, base + 1);
        unsigned p2 = __shfl(pv, base + 2), p3 = __shfl(pv, base + 3);
        unsigned p4 = __shfl(pv, base + 4), p5 = __shfl(pv, base + 5);
        unsigned p6 = __shfl(pv, base + 6), p7 = __shfl(pv, base + 7);
        {
            half8 r0 = in8[(p0 & 0xFFFFu) * 16 + t];
            half8 r1 = in8[(p1 & 0xFFFFu) * 16 + t];
            half8 r2 = in8[(p2 & 0xFFFFu) * 16 + t];
            half8 r3 = in8[(p3 & 0xFFFFu) * 16 + t];
            half8 r4 = in8[(p4 & 0xFFFFu) * 16 + t];
            half8 r5 = in8[(p5 & 0xFFFFu) * 16 + t];
            half8 r6 = in8[(p6 & 0xFFFFu) * 16 + t];
            half8 r7 = in8[(p7 & 0xFFFFu) * 16 + t];
            float w0f = hi2f(p0), w1f = hi2f(p1), w2f = hi2f(p2), w3f = hi2f(p3);
            float w4f = hi2f(p4), w5f = hi2f(p5), w6f = hi2f(p6), w7f = hi2f(p7);
#pragma unroll
            for (int j = 0; j < 8; j++) a[j] = fmaf((float)r0[j], w0f, a[j]);
#pragma unroll
            for (int j = 0; j < 8; j++) a[j] = fmaf((float)r1[j], w1f, a[j]);
#pragma unroll
            for (int j = 0; j < 8; j++) a[j] = fmaf((float)r2[j], w2f, a[j]);
#pragma unroll
            for (int j = 0; j < 8; j++) a[j] = fmaf((float)r3[j], w3f, a[j]);
#pragma unroll
            for (int j = 0; j < 8; j++) a[j] = fmaf((float)r4[j], w4f, a[j]);
#pragma unroll
            for (int j = 0; j < 8; j++) a[j] = fmaf((float)r5[j], w5f, a[j]);
#pragma unroll
            for (int j = 0; j < 8; j++) a[j] = fmaf((float)r6[j], w6f, a[j]);
#pragma unroll
            for (int j = 0; j < 8; j++) a[j] = fmaf((float)r7[j], w7f, a[j]);
        }
        if (w0 + 8 >= dm) continue;  // uniform branch: skip batch B if window <= 8 edges
        // batch B: edges 8..15
        p0 = __shfl(pv, base + 8);  p1 = __shfl(pv, base + 9);
        p2 = __shfl(pv, base + 10); p3 = __shfl(pv, base + 11);
        p4 = __shfl(pv, base + 12); p5 = __shfl(pv, base + 13);
        p6 = __shfl(pv, base + 14); p7 = __shfl(pv, base + 15);
        {
            half8 r0 = in8[(p0 & 0xFFFFu) * 16 + t];
            half8 r1 = in8[(p1 & 0xFFFFu) * 16 + t];
            half8 r2 = in8[(p2 & 0xFFFFu) * 16 + t];
            half8 r3 = in8[(p3 & 0xFFFFu) * 16 + t];
            half8 r4 = in8[(p4 & 0xFFFFu) * 16 + t];
            half8 r5 = in8[(p5 & 0xFFFFu) * 16 + t];
            half8 r6 = in8[(p6 & 0xFFFFu) * 16 + t];
            half8 r7 = in8[(p7 & 0xFFFFu) * 16 + t];
            float w0f = hi2f(p0), w1f = hi2f(p1), w2f = hi2f(p2), w3f = hi2f(p3);
            float w4f = hi2f(p4), w5f = hi2f(p5), w6f = hi2f(p6), w7f = hi2f(p7);
#pragma unroll
            for (int j = 0; j < 8; j++) a[j] = fmaf((float)r0[j], w0f, a[j]);
#pragma unroll
            for (int j = 0; j < 8; j++) a[j] = fmaf((float)r1[j], w1f, a[j]);
#pragma unroll
            for (int j = 0; j < 8; j++) a[j] = fmaf((float)r2[j], w2f, a[j]);
#pragma unroll
            for (int j = 0; j < 8; j++) a[j] = fmaf((float)r3[j], w3f, a[j]);
#pragma unroll
            for (int j = 0; j < 8; j++) a[j] = fmaf((float)r4[j], w4f, a[j]);
#pragma unroll
            for (int j = 0; j < 8; j++) a[j] = fmaf((float)r5[j], w5f, a[j]);
#pragma unroll
            for (int j = 0; j < 8; j++) a[j] = fmaf((float)r6[j], w6f, a[j]);
#pragma unroll
            for (int j = 0; j < 8; j++) a[j] = fmaf((float)r7[j], w7f, a[j]);
        }
    }
    // final dst scale + write: 64 lanes x 16B = 1KB contiguous per node
    _Float16 ob[8];
#pragma unroll
    for (int j = 0; j < 8; j++) ob[j] = (_Float16)(wn * a[j]);
    *(half8*)(Acat + (size_t)n * 512 + (base << 3) + t * 8) = *(half8*)ob;
}

// ---------------- MFMA GEMM: C[NN][128] = relu(A[NN][512] @ W[512][128] + bias) ----------------
// Bt staged in double-buffered LDS (BK=64, padded col stride 72 halves -> ds_read 2-way
// conflict = free). Per k-step: 1 global af + 8 ds_read + 8 MFMA. af prefetched one full
// chunk ahead. 4 waves/block x 16 rows, grid 782 (12 waves/CU). This removes R6's failure:
// VGPR=52 forced serialized bf global loads (8 x ~300cyc L2 latency per k-step).
template <bool STATS>
__global__ __launch_bounds__(256) void k_mm(const unsigned short* __restrict__ A,
                                            const unsigned short* __restrict__ Bt,
                                            const float* __restrict__ bias,
                                            unsigned short* __restrict__ C,
                                            float* __restrict__ bnsum) {
    __shared__ unsigned short btl[2][128 * 72];  // 2 x 18 KB
    int tid = threadIdx.x;
    int w = tid >> 6, lane = tid & 63;
    int ln = lane & 15, quad = lane >> 4;
    int m0 = blockIdx.x * 64 + w * 16;
    size_t arow = (size_t)min(m0 + ln, NN - 1) * 512;

    // staging map: thread t covers col=t>>1, 64B half s=t&1 of the 16KB chunk
    int scol = tid >> 1, ss = tid & 1;
    const unsigned short* sgp = Bt + (size_t)scol * 512 + ss * 32;
    unsigned short* slp0 = &btl[0][scol * 72 + ss * 32];
    unsigned short* slp1 = &btl[1][scol * 72 + ss * 32];

    // stage chunk 0 + prefetch af chunk 0
    {
        half8 v0 = *(const half8*)(sgp + 0);
        half8 v1 = *(const half8*)(sgp + 8);
        half8 v2 = *(const half8*)(sgp + 16);
        half8 v3 = *(const half8*)(sgp + 24);
        *(half8*)(slp0 + 0) = v0; *(half8*)(slp0 + 8) = v1;
        *(half8*)(slp0 + 16) = v2; *(half8*)(slp0 + 24) = v3;
    }
    half8 a0 = *(const half8*)(A + arow + quad * 8);
    half8 a1 = *(const half8*)(A + arow + 32 + quad * 8);
    __syncthreads();

    f32x4 acc[8];
#pragma unroll
    for (int b = 0; b < 8; b++) acc[b] = (f32x4){0.f, 0.f, 0.f, 0.f};

    for (int c = 0; c < 8; ++c) {  // 8 chunks of BK=64
        int cur = c & 1;
        half8 na0 = a0, na1 = a1;
        if (c < 7) {
            // stage next chunk into the other buffer + prefetch next af
            const unsigned short* gp = sgp + (c + 1) * 64;
            half8 v0 = *(const half8*)(gp + 0);
            half8 v1 = *(const half8*)(gp + 8);
            half8 v2 = *(const half8*)(gp + 16);
            half8 v3 = *(const half8*)(gp + 24);
            unsigned short* lp = cur ? slp0 : slp1;
            *(half8*)(lp + 0) = v0; *(half8*)(lp + 8) = v1;
            *(half8*)(lp + 16) = v2; *(half8*)(lp + 24) = v3;
            na0 = *(const half8*)(A + arow + (c + 1) * 64 + quad * 8);
            na1 = *(const half8*)(A + arow + (c + 1) * 64 + 32 + quad * 8);
        }
        // compute chunk c from btl[cur]
        const unsigned short* bb = btl[cur];
#pragma unroll
        for (int nf = 0; nf < 8; nf++) {
            half8 bf = *(const half8*)(bb + (nf * 16 + ln) * 72 + quad * 8);
            acc[nf] = __builtin_amdgcn_mfma_f32_16x16x32_f16(a0, bf, acc[nf], 0, 0, 0);
        }
#pragma unroll
        for (int nf = 0; nf < 8; nf++) {
            half8 bf = *(const half8*)(bb + (nf * 16 + ln) * 72 + 32 + quad * 8);
            acc[nf] = __builtin_amdgcn_mfma_f32_16x16x32_f16(a1, bf, acc[nf], 0, 0, 0);
        }
        a0 = na0; a1 = na1;
        __syncthreads();
    }

    float bs[8];
#pragma unroll
    for (int nf = 0; nf < 8; nf++) bs[nf] = bias[nf * 16 + ln];
    float sn[8], qn[8];
#pragma unroll
    for (int nf = 0; nf < 8; nf++) { sn[nf] = 0.f; qn[nf] = 0.f; }

#pragma unroll
    for (int nf = 0; nf < 8; nf++)
#pragma unroll
        for (int rg = 0; rg < 4; rg++) {
            int m = m0 + quad * 4 + rg;
            if (m < NN) {
                float v = fmaxf(acc[nf][rg] + bs[nf], 0.f);
                if (STATS) { sn[nf] += v; qn[nf] += v * v; }
                C[(size_t)m * 128 + nf * 16 + ln] = f2h_bits(v);
            }
        }

    if (STATS) {
#pragma unroll
        for (int nf = 0; nf < 8; nf++) {
            float s = sn[nf], q = qn[nf];
            s += __shfl_xor(s, 16); s += __shfl_xor(s, 32);
            q += __shfl_xor(q, 16); q += __shfl_xor(q, 32);
            if (quad == 0) {
                unsafeAtomicAdd(&bnsum[nf * 16 + ln], s);
                unsafeAtomicAdd(&bnsum[128 + nf * 16 + ln], q);
            }
        }
    }
}

// ---------------- final: BN affine + relu(BN(R2)@l1W+l1b)@l2W+l2b ----------------
// Wt3 (32 KB) staged ONCE into padded LDS; all 4 A-row loads issued upfront -> no
// serialized global bf loads. Grid 782.
__global__ __launch_bounds__(256) void k_final(const unsigned short* __restrict__ R2,
                                               const float* __restrict__ bnsum,
                                               const float* __restrict__ gamma,
                                               const float* __restrict__ beta,
                                               const unsigned short* __restrict__ Wt3,
                                               const float* __restrict__ l1b,
                                               const float* __restrict__ l2W,
                                               const float* __restrict__ l2b,
                                               float* __restrict__ out) {
    __shared__ float bnp_s[256];
    __shared__ unsigned short wl[128 * 136];  // 34 KB padded
    int tid = threadIdx.x;
    if (tid < 128) {
        float mean = bnsum[tid] / (float)NN;
        float var = bnsum[128 + tid] / (float)NN - mean * mean;
        float sc = gamma[tid] * rsqrtf(var + BN_EPS);
        bnp_s[tid] = sc;
        bnp_s[128 + tid] = beta[tid] - mean * sc;
    }
    // stage Wt3: thread t: col=t>>1, half s=t&1 covers k-halves s*64..+63
    {
        int col = tid >> 1, s = tid & 1;
        const unsigned short* gp = Wt3 + (size_t)col * 128 + s * 64;
        unsigned short* lp = wl + col * 136 + s * 64;
#pragma unroll
        for (int i = 0; i < 8; i++) *(half8*)(lp + i * 8) = *(const half8*)(gp + i * 8);
    }
    int w = tid >> 6, lane = tid & 63;
    int ln = lane & 15, quad = lane >> 4;
    int m0 = blockIdx.x * 64 + w * 16;
    size_t arow = (size_t)min(m0 + ln, NN - 1) * 128;
    // issue all A loads upfront (overlap with staging)
    half8 rv[4];
#pragma unroll
    for (int ks = 0; ks < 4; ks++) rv[ks] = *(const half8*)(R2 + arow + ks * 32 + quad * 8);
    __syncthreads();

    f32x4 acc[8];
#pragma unroll
    for (int b = 0; b < 8; b++) acc[b] = (f32x4){0.f, 0.f, 0.f, 0.f};

#pragma unroll
    for (int ks = 0; ks < 4; ks++) {
        int kof = ks * 32 + quad * 8;
        _Float16 ab[8];
#pragma unroll
        for (int j = 0; j < 8; j++)
            ab[j] = (_Float16)(fmaf((float)rv[ks][j], bnp_s[kof + j], bnp_s[128 + kof + j]));
        half8 af = *(half8*)ab;
#pragma unroll
        for (int nf = 0; nf < 8; nf++) {
            half8 bf = *(const half8*)(wl + (nf * 16 + ln) * 136 + kof);
            acc[nf] = __builtin_amdgcn_mfma_f32_16x16x32_f16(af, bf, acc[nf], 0, 0, 0);
        }
    }

    float b1v[8], w0[8], w1[8];
#pragma unroll
    for (int nf = 0; nf < 8; nf++) {
        int n = nf * 16 + ln;
        b1v[nf] = l1b[n];
        w0[nf] = l2W[n * 2];
        w1[nf] = l2W[n * 2 + 1];
    }
    float ob0 = l2b[0], ob1 = l2b[1];
#pragma unroll
    for (int rg = 0; rg < 4; rg++) {
        float p0 = 0.f, p1 = 0.f;
#pragma unroll
        for (int nf = 0; nf < 8; nf++) {
            float y = fmaxf(acc[nf][rg] + b1v[nf], 0.f);
            p0 += y * w0[nf];
            p1 += y * w1[nf];
        }
        p0 += __shfl_xor(p0, 1); p0 += __shfl_xor(p0, 2);
        p0 += __shfl_xor(p0, 4); p0 += __shfl_xor(p0, 8);
        p1 += __shfl_xor(p1, 1); p1 += __shfl_xor(p1, 2);
        p1 += __shfl_xor(p1, 4); p1 += __shfl_xor(p1, 8);
        int m = m0 + quad * 4 + rg;
        if (ln == 0 && m < NN) {
            out[(size_t)m * 2 + 0] = p0 + ob0;
            out[(size_t)m * 2 + 1] = p1 + ob1;
        }
    }
}

extern "C" void kernel_launch(void* const* d_in, const int* in_sizes, int n_in,
                              void* d_out, int out_size, void* d_ws, size_t ws_size,
                              hipStream_t stream) {
    const float* x = (const float*)d_in[0];
    const int* ei = (const int*)d_in[1];
    const float* W1 = (const float*)d_in[2];
    const float* b1 = (const float*)d_in[3];
    const float* W2 = (const float*)d_in[4];
    const float* b2 = (const float*)d_in[5];
    const float* gamma = (const float*)d_in[6];
    const float* beta = (const float*)d_in[7];
    const float* l1W = (const float*)d_in[8];
    const float* l1b = (const float*)d_in[9];
    const float* l2W = (const float*)d_in[10];
    const float* l2b = (const float*)d_in[11];
    float* out = (float*)d_out;

    char* ws = (char*)d_ws;
    size_t off = 0;
    auto alloc = [&](size_t bytes) {
        void* p = ws + off;
        off += (bytes + 255) & ~(size_t)255;
        return p;
    };
    float* dinv = (float*)alloc((size_t)NREL * NN * sizeof(float));
    int* rstart = (int*)alloc((size_t)NREL * NN * sizeof(int));
    int* rend = (int*)alloc((size_t)NREL * NN * sizeof(int));
    unsigned short* csr = (unsigned short*)alloc((size_t)NBK * BCAP * 2);            // 4.8 MB
    unsigned* wpack = (unsigned*)alloc((size_t)NBK * BCAP * 4);                      // 9.6 MB
    unsigned short* xb = (unsigned short*)alloc((size_t)NN * D * 2);                 // 12.8 MB
    unsigned short* Acat = (unsigned short*)alloc((size_t)NN * 512 * 2);             // 51.2 MB
    unsigned short* h1b = (unsigned short*)alloc((size_t)NN * D * 2);                // 12.8 MB
    unsigned short* R2b = (unsigned short*)alloc((size_t)NN * D * 2);                // 12.8 MB
    unsigned short* Wt1 = (unsigned short*)alloc(128 * 512 * 2);
    unsigned short* Wt2 = (unsigned short*)alloc(128 * 512 * 2);
    unsigned short* Wt3 = (unsigned short*)alloc(128 * 128 * 2);
    float* bs1 = (float*)alloc(128 * sizeof(float));
    float* bs2 = (float*)alloc(128 * sizeof(float));
    float* bnsum = (float*)alloc(256 * sizeof(float));

    // frag/cntg alias Acat's storage (dead once k_sortb completes; Acat first written by k_agg)
    int* frag = (int*)Acat;                                       // 19.3 MB
    int* cntg = frag + (size_t)NREL * NRANGE * NCH * FCAP;        // 0.2 MB

    k_pre<<<CAST_BLKS + 321, 256, 0, stream>>>(x, W1, W2, l1W, b1, b2, xb, Wt1, Wt2, Wt3,
                                               bs1, bs2, bnsum);
    dim3 bgrid(NCH, NREL);
    k_bin<<<bgrid, 256, 0, stream>>>(ei, frag, cntg);
    dim3 sgrid(NRANGE, NREL);
    k_sortb<<<sgrid, 512, 0, stream>>>(frag, cntg, csr, rstart, rend, dinv);
    k_wei<<<(NBK * BCAP) / 256, 256, 0, stream>>>(csr, dinv, wpack);

    int agrid = (NN + 3) / 4;     // wave = node (all 4 relations)
    int mgrid = (NN + 63) / 64;   // 64 rows per block
    // layer 1: aggregate x per relation -> Acat (concat), then one K=512 GEMM
    k_agg<<<agrid, 256, 0, stream>>>(xb, wpack, rstart, rend, dinv, Acat);
    k_mm<false><<<mgrid, 256, 0, stream>>>(Acat, Wt1, bs1, h1b, nullptr);
    // layer 2
    k_agg<<<agrid, 256, 0, stream>>>(h1b, wpack, rstart, rend, dinv, Acat);
    k_mm<true><<<mgrid, 256, 0, stream>>>(Acat, Wt2, bs2, R2b, bnsum);
    // fused BN + MLP head
    k_final<<<mgrid, 256, 0, stream>>>(R2b, bnsum, gamma, beta, Wt3, l1b, l2W, l2b, out);
}

// Round 8
// 357.191 us; speedup vs baseline: 1.3708x; 1.1061x over previous
//
#include <hip/hip_runtime.h>
#include <math.h>

#define NN 50000
#define NE 500000
#define NREL 4
#define D 128
#define RSZ 512                 // dst-range size (one bin)
#define NRANGE 98               // ceil(NN/512)
#define NBK (NREL * NRANGE)     // 392 sort blocks
#define BCAP 6144               // per-(range,rel) csr capacity (mean 5120, +14 sigma)
#define NCH 128                 // edge chunks per relation
#define CH 3907                 // edges per chunk (128*3907 >= 500000)
#define FCAP 96                 // frag capacity per (chunk,bin): mean 40, +9 sigma
#define CAST_BLKS 6250          // NN*D/4/256
static constexpr float BN_EPS = 1e-5f;

typedef __attribute__((ext_vector_type(8))) _Float16 half8;
typedef __attribute__((ext_vector_type(4))) float f32x4;

__device__ __forceinline__ unsigned short f2h_bits(float f) {
    _Float16 h = (_Float16)f;  // v_cvt_f16_f32 (RTNE)
    return __builtin_bit_cast(unsigned short, h);
}
__device__ __forceinline__ float hi2f(unsigned p) {  // f16 in high 16 bits -> f32
    return (float)__builtin_bit_cast(_Float16, (unsigned short)(p >> 16));
}

// ---------------- fused prologue: cast x->f16, weight transpose+cast, bias sums, bnsum zero ----
__global__ __launch_bounds__(256) void k_pre(const float* __restrict__ x,
                                             const float* __restrict__ W1, const float* __restrict__ W2,
                                             const float* __restrict__ l1W, const float* __restrict__ b1,
                                             const float* __restrict__ b2,
                                             unsigned short* __restrict__ xb,
                                             unsigned short* __restrict__ Wt1,
                                             unsigned short* __restrict__ Wt2,
                                             unsigned short* __restrict__ Wt3,
                                             float* __restrict__ bs1, float* __restrict__ bs2,
                                             float* __restrict__ bnsum) {
    int blk = blockIdx.x, tid = threadIdx.x;
    if (blk < CAST_BLKS) {
        int i = blk * 256 + tid;
        float4 v = *(const float4*)(x + (size_t)i * 4);
        unsigned short u[4] = {f2h_bits(v.x), f2h_bits(v.y), f2h_bits(v.z), f2h_bits(v.w)};
        *(ushort4*)(xb + (size_t)i * 4) = *(ushort4*)u;
    } else if (blk < CAST_BLKS + 256) {
        int i = (blk - CAST_BLKS) * 256 + tid;  // [0, 65536)
        int kk = i & 511, n = i >> 9;           // coalesced stores along kk
        Wt1[n * 512 + kk] = f2h_bits(W1[kk * 128 + n]);
        Wt2[n * 512 + kk] = f2h_bits(W2[kk * 128 + n]);
    } else if (blk < CAST_BLKS + 320) {
        int i = (blk - CAST_BLKS - 256) * 256 + tid;  // [0, 16384)
        int kk = i & 127, n = i >> 7;
        Wt3[n * 128 + kk] = f2h_bits(l1W[kk * 128 + n]);
    } else {
        if (tid < 128) {
            bs1[tid] = b1[tid] + b1[128 + tid] + b1[256 + tid] + b1[384 + tid];
            bs2[tid] = b2[tid] + b2[128 + tid] + b2[256 + tid] + b2[384 + tid];
        }
        bnsum[tid] = 0.f;  // 256 floats
    }
}

// ---------------- pass A: bin edges into (chunk, range) fragment windows ----------------
// packed = src | dstlocal<<16 (src<50000 fits 16 bits, dstlocal 9 bits)
__global__ __launch_bounds__(256) void k_bin(const int* __restrict__ ei,
                                             int* __restrict__ frag,
                                             int* __restrict__ cntg) {
    int c = blockIdx.x, r = blockIdx.y;
    const int* srcp = ei + r * 2 * NE;
    const int* dstp = srcp + NE;
    __shared__ int bins[NRANGE * FCAP];  // 37.6 KB
    __shared__ int cnt[NRANGE];
    int tid = threadIdx.x;
    for (int i = tid; i < NRANGE; i += 256) cnt[i] = 0;
    __syncthreads();
    int e0 = c * CH, e1 = min(e0 + CH, NE);
    for (int e = e0 + tid; e < e1; e += 256) {
        int d = dstp[e];
        int s = srcp[e];
        int q = d >> 9;
        int pos = atomicAdd(&cnt[q], 1);
        if (pos < FCAP) bins[q * FCAP + pos] = s | ((d & 511) << 16);
    }
    __syncthreads();
    int w = tid >> 6, lane = tid & 63;
    for (int q = w; q < NRANGE; q += 4) {
        int k = min(cnt[q], FCAP);
        int gbase = ((r * NRANGE + q) * NCH + c) * FCAP;
        for (int i = lane; i < k; i += 64) frag[gbase + i] = bins[q * FCAP + i];
    }
    for (int q = tid; q < NRANGE; q += 256) cntg[(r * NRANGE + q) * NCH + c] = min(cnt[q], FCAP);
}

// ---------------- pass B: per (range, rel) counting-sort into CSR ----------------
__global__ __launch_bounds__(512) void k_sortb(const int* __restrict__ frag,
                                               const int* __restrict__ cntg,
                                               unsigned short* __restrict__ csr,
                                               int* __restrict__ rstart,
                                               int* __restrict__ rend,
                                               float* __restrict__ dinv) {
    int q = blockIdx.x, r = blockIdx.y;
    int blk = r * NRANGE + q;
    int n0 = q * RSZ;
    int nrows = min(RSZ, NN - n0);
    __shared__ int cnts[NCH], cbase[NCH];
    __shared__ int stage[BCAP];          // 24 KB
    __shared__ unsigned short csr_s[BCAP];
    __shared__ int hist[RSZ], off[RSZ], cnt2[RSZ];
    int tid = threadIdx.x;
    hist[tid] = 0;
    cnt2[tid] = 0;
    if (tid < NCH) cnts[tid] = cntg[blk * NCH + tid];
    __syncthreads();
    // exclusive scan of 128 chunk counts
    if (tid < NCH) cbase[tid] = cnts[tid];
    __syncthreads();
    for (int d = 1; d < NCH; d <<= 1) {
        int t = 0;
        if (tid < NCH && tid >= d) t = cbase[tid - d];
        __syncthreads();
        if (tid < NCH) cbase[tid] += t;
        __syncthreads();
    }
    if (tid < NCH) cbase[tid] -= cnts[tid];
    __syncthreads();
    int tot = cbase[NCH - 1] + cnts[NCH - 1];
    // parallel gather of all 128 fragment windows (4 threads per chunk)
    {
        int g = tid >> 2, l = tid & 3;
        int k = cnts[g], cb = cbase[g];
        int gbase = (blk * NCH + g) * FCAP;
        for (int i = l; i < k; i += 4)
            if (cb + i < BCAP) stage[cb + i] = frag[gbase + i];
    }
    __syncthreads();
    if (tot > BCAP) tot = BCAP;
    // histogram over dst-local
    for (int i = tid; i < tot; i += 512) atomicAdd(&hist[(stage[i] >> 16) & 511], 1);
    __syncthreads();
    int h = hist[tid];
    if (tid < nrows) dinv[r * NN + n0 + tid] = rsqrtf((float)(h + 1));  // +1 self loop
    // inclusive scan -> exclusive offsets
    off[tid] = h;
    __syncthreads();
    for (int d = 1; d < RSZ; d <<= 1) {
        int t = (tid >= d) ? off[tid - d] : 0;
        __syncthreads();
        off[tid] += t;
        __syncthreads();
    }
    int excl = off[tid] - h;
    __syncthreads();
    off[tid] = excl;
    int base = blk * BCAP;
    if (tid < nrows) {
        rstart[r * NN + n0 + tid] = base + excl;
        rend[r * NN + n0 + tid] = base + excl + h;
    }
    __syncthreads();
    // counting-sort into LDS
    for (int i = tid; i < tot; i += 512) {
        int v = stage[i];
        int dl = (v >> 16) & 511;
        int p = atomicAdd(&cnt2[dl], 1);
        csr_s[off[dl] + p] = (unsigned short)(v & 0xFFFF);
    }
    __syncthreads();
    // coalesced block-private write-out
    for (int i = tid; i < tot; i += 512) csr[base + i] = csr_s[i];
}

// ---------------- fill packed per-edge words: wpack[i] = src | f16(dinv[r][src])<<16 ----------
__global__ __launch_bounds__(256) void k_wei(const unsigned short* __restrict__ csr,
                                             const float* __restrict__ dinv,
                                             unsigned* __restrict__ wpack) {
    int gi = blockIdx.x * 256 + threadIdx.x;
    int r = gi / (NRANGE * BCAP);
    int s = csr[gi];                       // garbage in gaps is harmless (masked in k_agg)
    float w = dinv[r * NN + min(s, NN - 1)];
    wpack[gi] = (unsigned)s | ((unsigned)f2h_bits(w) << 16);
}

// ---------------- aggregation: wave = node, quarter = relation (R3 structure, 67us) ----------
__global__ __launch_bounds__(256) void k_agg(const unsigned short* __restrict__ in,  // f16 [NN][128]
                                             const unsigned* __restrict__ wpack,
                                             const int* __restrict__ rstart,
                                             const int* __restrict__ rend,
                                             const float* __restrict__ dinv,         // [NREL][NN]
                                             unsigned short* __restrict__ Acat) {    // f16 [NN][512]
    int wave = threadIdx.x >> 6, lane = threadIdx.x & 63;
    int n = blockIdx.x * 4 + wave;
    if (n >= NN) return;
    int t = lane & 15;
    int base = lane & 48;  // q<<4
    int nb = (base >> 4) * NN + n;  // q*NN + n
    const half8* in8 = (const half8*)in;
    float wn = dinv[nb];
    int start = rstart[nb];
    int deg = rend[nb] - start;
    // wave-uniform max degree over the 4 quarters -> branchless uniform trip
    int dm = deg;
    dm = max(dm, __shfl_xor(dm, 16));
    dm = max(dm, __shfl_xor(dm, 32));
    // acc init = self-loop contribution (wn * x_n); final scale by wn at the end
    half8 us = in8[(size_t)n * 16 + t];
    float a[8];
#pragma unroll
    for (int j = 0; j < 8; j++) a[j] = wn * (float)us[j];

    for (int w0 = 0; w0 < dm; w0 += 16) {
        // cooperative window: lane holds edge (w0 + t) of ITS quarter's list
        int li = w0 + t;
        int gi = min(start + li, NBK * BCAP - 1);
        unsigned pv = wpack[gi];
        if (li >= deg) pv = 0u;  // src=0, w=+0.0 (row 0 load, L1-hot, adds zero)
        // batch A: edges 0..7 of this window
        unsigned p0 = __shfl(pv, base + 0), p1 = __shfl(pv, base + 1);
        unsigned p2 = __shfl(pv, base + 2), p3 = __shfl(pv, base + 3);
        unsigned p4 = __shfl(pv, base + 4), p5 = __shfl(pv, base + 5);
        unsigned p6 = __shfl(pv, base + 6), p7 = __shfl(pv, base + 7);
        {
            half8 r0 = in8[(p0 & 0xFFFFu) * 16 + t];
            half8 r1 = in8[(p1 & 0xFFFFu) * 16 + t];
            half8 r2 = in8[(p2 & 0xFFFFu) * 16 + t];
            half8 r3 = in8[(p3 & 0xFFFFu) * 16 + t];
            half8 r4 = in8[(p4 & 0xFFFFu) * 16 + t];
            half8 r5 = in8[(p5 & 0xFFFFu) * 16 + t];
            half8 r6 = in8[(p6 & 0xFFFFu) * 16 + t];
            half8 r7 = in8[(p7 & 0xFFFFu) * 16 + t];
            float w0f = hi2f(p0), w1f = hi2f(p1), w2f = hi2f(p2), w3f = hi2f(p3);
            float w4f = hi2f(p4), w5f = hi2f(p5), w6f = hi2f(p6), w7f = hi2f(p7);
#pragma unroll
            for (int j = 0; j < 8; j++) a[j] = fmaf((float)r0[j], w0f, a[j]);
#pragma unroll
            for (int j = 0; j < 8; j++) a[j] = fmaf((float)r1[j], w1f, a[j]);
#pragma unroll
            for (int j = 0; j < 8; j++) a[j] = fmaf((float)r2[j], w2f, a[j]);
#pragma unroll
            for (int j = 0; j < 8; j++) a[j] = fmaf((float)r3[j], w3f, a[j]);
#pragma unroll
            for (int j = 0; j < 8; j++) a[j] = fmaf((float)r4[j], w4f, a[j]);
#pragma unroll
            for (int j = 0; j < 8; j++) a[j] = fmaf((float)r5[j], w5f, a[j]);
#pragma unroll
            for (int j = 0; j < 8; j++) a[j] = fmaf((float)r6[j], w6f, a[j]);
#pragma unroll
            for (int j = 0; j < 8; j++) a[j] = fmaf((float)r7[j], w7f, a[j]);
        }
        if (w0 + 8 >= dm) continue;  // uniform branch: skip batch B if window <= 8 edges
        // batch B: edges 8..15
        p0 = __shfl(pv, base + 8);  p1 = __shfl(pv, base + 9);
        p2 = __shfl(pv, base + 10); p3 = __shfl(pv, base + 11);
        p4 = __shfl(pv, base + 12); p5 = __shfl(pv, base + 13);
        p6 = __shfl(pv, base + 14); p7 = __shfl(pv, base + 15);
        {
            half8 r0 = in8[(p0 & 0xFFFFu) * 16 + t];
            half8 r1 = in8[(p1 & 0xFFFFu) * 16 + t];
            half8 r2 = in8[(p2 & 0xFFFFu) * 16 + t];
            half8 r3 = in8[(p3 & 0xFFFFu) * 16 + t];
            half8 r4 = in8[(p4 & 0xFFFFu) * 16 + t];
            half8 r5 = in8[(p5 & 0xFFFFu) * 16 + t];
            half8 r6 = in8[(p6 & 0xFFFFu) * 16 + t];
            half8 r7 = in8[(p7 & 0xFFFFu) * 16 + t];
            float w0f = hi2f(p0), w1f = hi2f(p1), w2f = hi2f(p2), w3f = hi2f(p3);
            float w4f = hi2f(p4), w5f = hi2f(p5), w6f = hi2f(p6), w7f = hi2f(p7);
#pragma unroll
            for (int j = 0; j < 8; j++) a[j] = fmaf((float)r0[j], w0f, a[j]);
#pragma unroll
            for (int j = 0; j < 8; j++) a[j] = fmaf((float)r1[j], w1f, a[j]);
#pragma unroll
            for (int j = 0; j < 8; j++) a[j] = fmaf((float)r2[j], w2f, a[j]);
#pragma unroll
            for (int j = 0; j < 8; j++) a[j] = fmaf((float)r3[j], w3f, a[j]);
#pragma unroll
            for (int j = 0; j < 8; j++) a[j] = fmaf((float)r4[j], w4f, a[j]);
#pragma unroll
            for (int j = 0; j < 8; j++) a[j] = fmaf((float)r5[j], w5f, a[j]);
#pragma unroll
            for (int j = 0; j < 8; j++) a[j] = fmaf((float)r6[j], w6f, a[j]);
#pragma unroll
            for (int j = 0; j < 8; j++) a[j] = fmaf((float)r7[j], w7f, a[j]);
        }
    }
    // final dst scale + write: 64 lanes x 16B = 1KB contiguous per node
    _Float16 ob[8];
#pragma unroll
    for (int j = 0; j < 8; j++) ob[j] = (_Float16)(wn * a[j]);
    *(half8*)(Acat + (size_t)n * 512 + (base << 3) + t * 8) = *(half8*)ob;
}

// ---------------- MFMA GEMM: C[NN][128] = relu(A[NN][512] @ W[512][128] + bias) ----------------
// Whole Bt (128 KB) staged ONCE into 134 KB LDS (stride 524 halves: dword-stride 6 mod 32 ->
// 16 distinct start banks, ~2-way = free). ONE barrier total; inner loop is barrier-free:
// per k-step 2 global af + 8 ds_read (each bf feeds 2 MFMAs) + 16 MFMA. 512 thr / 8 waves,
// __launch_bounds__(512,2) -> 256-VGPR budget so the compiler can pipeline af loads (R6/R7
// failed because a 52-VGPR allocation serialized every prefetch).
// Grid 250 x 200 rows exact; waves span 256 rows -> store/stats guarded at m < b0+200.
template <bool STATS>
__global__ __launch_bounds__(512, 2) void k_mm(const unsigned short* __restrict__ A,
                                               const unsigned short* __restrict__ Bt,
                                               const float* __restrict__ bias,
                                               unsigned short* __restrict__ C,
                                               float* __restrict__ bnsum) {
    constexpr int LDP = 524;
    __shared__ unsigned short wl[128 * LDP];  // 134 KB
    int tid = threadIdx.x;
    int wave = tid >> 6, lane = tid & 63;
    int ln = lane & 15, quad = lane >> 4;
    // stage whole Bt [128][512] -> LDS (coalesced 16B/lane; wave writes whole 1KB cols)
#pragma unroll
    for (int i = 0; i < 16; ++i) {
        int h = tid + i * 512;          // half8 index, 0..8191
        int col = h >> 6;
        int k = (h & 63) * 8;
        *(half8*)(wl + col * LDP + k) = *(const half8*)(Bt + (size_t)h * 8);
    }
    int b0 = blockIdx.x * 200;
    int m0 = b0 + wave * 32;
    int mEnd = b0 + 200;                 // guard: rows >= mEnd belong to the next block
    size_t arow0 = (size_t)min(m0 + ln, NN - 1) * 512;
    size_t arow1 = (size_t)min(m0 + 16 + ln, NN - 1) * 512;
    __syncthreads();

    f32x4 acc[2][8];
#pragma unroll
    for (int a = 0; a < 2; a++)
#pragma unroll
        for (int b = 0; b < 8; b++) acc[a][b] = (f32x4){0.f, 0.f, 0.f, 0.f};

#pragma unroll
    for (int ks = 0; ks < 16; ++ks) {
        int kof = ks * 32 + quad * 8;
        half8 a0 = *(const half8*)(A + arow0 + kof);
        half8 a1 = *(const half8*)(A + arow1 + kof);
#pragma unroll
        for (int nf = 0; nf < 8; nf++) {
            half8 bf = *(const half8*)(wl + (nf * 16 + ln) * LDP + kof);
            acc[0][nf] = __builtin_amdgcn_mfma_f32_16x16x32_f16(a0, bf, acc[0][nf], 0, 0, 0);
            acc[1][nf] = __builtin_amdgcn_mfma_f32_16x16x32_f16(a1, bf, acc[1][nf], 0, 0, 0);
        }
    }

    float bs[8];
#pragma unroll
    for (int nf = 0; nf < 8; nf++) bs[nf] = bias[nf * 16 + ln];
    float sn[8], qn[8];
#pragma unroll
    for (int nf = 0; nf < 8; nf++) { sn[nf] = 0.f; qn[nf] = 0.f; }

#pragma unroll
    for (int mf = 0; mf < 2; mf++)
#pragma unroll
        for (int nf = 0; nf < 8; nf++)
#pragma unroll
            for (int rg = 0; rg < 4; rg++) {
                int m = m0 + mf * 16 + quad * 4 + rg;
                if (m < mEnd && m < NN) {
                    float v = fmaxf(acc[mf][nf][rg] + bs[nf], 0.f);
                    if (STATS) { sn[nf] += v; qn[nf] += v * v; }
                    C[(size_t)m * 128 + nf * 16 + ln] = f2h_bits(v);
                }
            }

    if (STATS) {
#pragma unroll
        for (int nf = 0; nf < 8; nf++) {
            float s = sn[nf], q = qn[nf];
            s += __shfl_xor(s, 16); s += __shfl_xor(s, 32);
            q += __shfl_xor(q, 16); q += __shfl_xor(q, 32);
            if (quad == 0) {
                unsafeAtomicAdd(&bnsum[nf * 16 + ln], s);
                unsafeAtomicAdd(&bnsum[128 + nf * 16 + ln], q);
            }
        }
    }
}

// ---------------- final: BN affine + relu(BN(R2)@l1W+l1b)@l2W+l2b ----------------
// Wt3 (32 KB) staged ONCE into padded LDS; all 4 A-row loads issued upfront -> no
// serialized global bf loads. Grid 782.
__global__ __launch_bounds__(256) void k_final(const unsigned short* __restrict__ R2,
                                               const float* __restrict__ bnsum,
                                               const float* __restrict__ gamma,
                                               const float* __restrict__ beta,
                                               const unsigned short* __restrict__ Wt3,
                                               const float* __restrict__ l1b,
                                               const float* __restrict__ l2W,
                                               const float* __restrict__ l2b,
                                               float* __restrict__ out) {
    __shared__ float bnp_s[256];
    __shared__ unsigned short wl[128 * 136];  // 34 KB padded
    int tid = threadIdx.x;
    if (tid < 128) {
        float mean = bnsum[tid] / (float)NN;
        float var = bnsum[128 + tid] / (float)NN - mean * mean;
        float sc = gamma[tid] * rsqrtf(var + BN_EPS);
        bnp_s[tid] = sc;
        bnp_s[128 + tid] = beta[tid] - mean * sc;
    }
    // stage Wt3: thread t: col=t>>1, half s=t&1 covers k-halves s*64..+63
    {
        int col = tid >> 1, s = tid & 1;
        const unsigned short* gp = Wt3 + (size_t)col * 128 + s * 64;
        unsigned short* lp = wl + col * 136 + s * 64;
#pragma unroll
        for (int i = 0; i < 8; i++) *(half8*)(lp + i * 8) = *(const half8*)(gp + i * 8);
    }
    int w = tid >> 6, lane = tid & 63;
    int ln = lane & 15, quad = lane >> 4;
    int m0 = blockIdx.x * 64 + w * 16;
    size_t arow = (size_t)min(m0 + ln, NN - 1) * 128;
    // issue all A loads upfront (overlap with staging)
    half8 rv[4];
#pragma unroll
    for (int ks = 0; ks < 4; ks++) rv[ks] = *(const half8*)(R2 + arow + ks * 32 + quad * 8);
    __syncthreads();

    f32x4 acc[8];
#pragma unroll
    for (int b = 0; b < 8; b++) acc[b] = (f32x4){0.f, 0.f, 0.f, 0.f};

#pragma unroll
    for (int ks = 0; ks < 4; ks++) {
        int kof = ks * 32 + quad * 8;
        _Float16 ab[8];
#pragma unroll
        for (int j = 0; j < 8; j++)
            ab[j] = (_Float16)(fmaf((float)rv[ks][j], bnp_s[kof + j], bnp_s[128 + kof + j]));
        half8 af = *(half8*)ab;
#pragma unroll
        for (int nf = 0; nf < 8; nf++) {
            half8 bf = *(const half8*)(wl + (nf * 16 + ln) * 136 + kof);
            acc[nf] = __builtin_amdgcn_mfma_f32_16x16x32_f16(af, bf, acc[nf], 0, 0, 0);
        }
    }

    float b1v[8], w0[8], w1[8];
#pragma unroll
    for (int nf = 0; nf < 8; nf++) {
        int n = nf * 16 + ln;
        b1v[nf] = l1b[n];
        w0[nf] = l2W[n * 2];
        w1[nf] = l2W[n * 2 + 1];
    }
    float ob0 = l2b[0], ob1 = l2b[1];
#pragma unroll
    for (int rg = 0; rg < 4; rg++) {
        float p0 = 0.f, p1 = 0.f;
#pragma unroll
        for (int nf = 0; nf < 8; nf++) {
            float y = fmaxf(acc[nf][rg] + b1v[nf], 0.f);
            p0 += y * w0[nf];
            p1 += y * w1[nf];
        }
        p0 += __shfl_xor(p0, 1); p0 += __shfl_xor(p0, 2);
        p0 += __shfl_xor(p0, 4); p0 += __shfl_xor(p0, 8);
        p1 += __shfl_xor(p1, 1); p1 += __shfl_xor(p1, 2);
        p1 += __shfl_xor(p1, 4); p1 += __shfl_xor(p1, 8);
        int m = m0 + quad * 4 + rg;
        if (ln == 0 && m < NN) {
            out[(size_t)m * 2 + 0] = p0 + ob0;
            out[(size_t)m * 2 + 1] = p1 + ob1;
        }
    }
}

extern "C" void kernel_launch(void* const* d_in, const int* in_sizes, int n_in,
                              void* d_out, int out_size, void* d_ws, size_t ws_size,
                              hipStream_t stream) {
    const float* x = (const float*)d_in[0];
    const int* ei = (const int*)d_in[1];
    const float* W1 = (const float*)d_in[2];
    const float* b1 = (const float*)d_in[3];
    const float* W2 = (const float*)d_in[4];
    const float* b2 = (const float*)d_in[5];
    const float* gamma = (const float*)d_in[6];
    const float* beta = (const float*)d_in[7];
    const float* l1W = (const float*)d_in[8];
    const float* l1b = (const float*)d_in[9];
    const float* l2W = (const float*)d_in[10];
    const float* l2b = (const float*)d_in[11];
    float* out = (float*)d_out;

    char* ws = (char*)d_ws;
    size_t off = 0;
    auto alloc = [&](size_t bytes) {
        void* p = ws + off;
        off += (bytes + 255) & ~(size_t)255;
        return p;
    };
    float* dinv = (float*)alloc((size_t)NREL * NN * sizeof(float));
    int* rstart = (int*)alloc((size_t)NREL * NN * sizeof(int));
    int* rend = (int*)alloc((size_t)NREL * NN * sizeof(int));
    unsigned short* csr = (unsigned short*)alloc((size_t)NBK * BCAP * 2);            // 4.8 MB
    unsigned* wpack = (unsigned*)alloc((size_t)NBK * BCAP * 4);                      // 9.6 MB
    unsigned short* xb = (unsigned short*)alloc((size_t)NN * D * 2);                 // 12.8 MB
    unsigned short* Acat = (unsigned short*)alloc((size_t)NN * 512 * 2);             // 51.2 MB
    unsigned short* h1b = (unsigned short*)alloc((size_t)NN * D * 2);                // 12.8 MB
    unsigned short* R2b = (unsigned short*)alloc((size_t)NN * D * 2);                // 12.8 MB
    unsigned short* Wt1 = (unsigned short*)alloc(128 * 512 * 2);
    unsigned short* Wt2 = (unsigned short*)alloc(128 * 512 * 2);
    unsigned short* Wt3 = (unsigned short*)alloc(128 * 128 * 2);
    float* bs1 = (float*)alloc(128 * sizeof(float));
    float* bs2 = (float*)alloc(128 * sizeof(float));
    float* bnsum = (float*)alloc(256 * sizeof(float));

    // frag/cntg alias Acat's storage (dead once k_sortb completes; Acat first written by k_agg)
    int* frag = (int*)Acat;                                       // 19.3 MB
    int* cntg = frag + (size_t)NREL * NRANGE * NCH * FCAP;        // 0.2 MB

    k_pre<<<CAST_BLKS + 321, 256, 0, stream>>>(x, W1, W2, l1W, b1, b2, xb, Wt1, Wt2, Wt3,
                                               bs1, bs2, bnsum);
    dim3 bgrid(NCH, NREL);
    k_bin<<<bgrid, 256, 0, stream>>>(ei, frag, cntg);
    dim3 sgrid(NRANGE, NREL);
    k_sortb<<<sgrid, 512, 0, stream>>>(frag, cntg, csr, rstart, rend, dinv);
    k_wei<<<(NBK * BCAP) / 256, 256, 0, stream>>>(csr, dinv, wpack);

    int agrid = (NN + 3) / 4;   // wave = node (all 4 relations)
    int mgrid = 250;            // 200 rows per block (exact: 250*200 = 50000)
    int fgrid = (NN + 63) / 64;
    // layer 1: aggregate x per relation -> Acat (concat), then one K=512 GEMM
    k_agg<<<agrid, 256, 0, stream>>>(xb, wpack, rstart, rend, dinv, Acat);
    k_mm<false><<<mgrid, 512, 0, stream>>>(Acat, Wt1, bs1, h1b, nullptr);
    // layer 2
    k_agg<<<agrid, 256, 0, stream>>>(h1b, wpack, rstart, rend, dinv, Acat);
    k_mm<true><<<mgrid, 512, 0, stream>>>(Acat, Wt2, bs2, R2b, bnsum);
    // fused BN + MLP head
    k_final<<<fgrid, 256, 0, stream>>>(R2b, bnsum, gamma, beta, Wt3, l1b, l2W, l2b, out);
}